// Round 6
// baseline (313.069 us; speedup 1.0000x reference)
//
#include <hip/hip_runtime.h>
#include <hip/hip_fp16.h>

// VectorBasis R6. R3-R5 lesson: LDS lane-atomics serialize ~4.4 cyc/op/CU;
// R5 still spent ~46 us on 4 atomics/record (histogram+scatter x 2 phases).
// R6 removes ALL per-record LDS atomics via ballot clustering + per-wave
// histogram rows (radix-sort counting pass):
//   rank = popc(same_key_mask & lanes_below); leader does plain RMW on its
//   wave's private histogram row; column scan + wave-shuffle scan give exact
//   sorted slots. Phase2's 4 sub-blocks/bin finish with a done-counter; the
//   last one sums the 4 partials into out (reduce kernel deleted).

constexpr int NSP  = 4;
constexpr int NRAD = 8;
constexpr int NPS  = 4;
constexpr int DDIM = NRAD * NPS;       // 32

constexpr int APB      = 512;          // atoms per bin
constexpr int APB_SH   = 9;
constexpr int NBIN_MAX = 256;
constexpr int SPLIT    = 4;            // phase2 sub-blocks per bin
constexpr int PH1_BLK  = 512;          // 8 waves
constexpr int PH1_U    = 4;
constexpr int PH1_REC  = PH1_BLK * PH1_U;  // 2048 records/block
constexpr int CAP2     = 3072;         // phase2 slice capacity
constexpr int IT2_MAX  = CAP2 / 256;   // 12
constexpr int PBSZ     = APB * 9;      // 4608 floats per partial chunk

__device__ __forceinline__ unsigned pack2(float a, float b) {
    union { __half2 h; unsigned u; } cv;
    cv.h = __floats2half2_rn(a, b);
    return cv.u;
}
__device__ __forceinline__ float2 unpack2(unsigned u) {
    union { unsigned u; __half2 h; } cv;
    cv.u = u;
    return __half22float2(cv.h);
}

__device__ __forceinline__ void build_w2(
    float* sW2, const float* cemb, const float* Wc, const float* W_alch,
    int tid, int nthreads)
{
    for (int i = tid; i < 3 * NRAD * 16; i += nthreads) {
        int p  = i & 15;
        int n  = (i >> 4) & 7;
        int o  = i >> 7;
        int sc = p >> 2, sn = p & 3;
        float w = 0.0f;
        #pragma unroll
        for (int q = 0; q < NPS; q++)
            w += cemb[sc * DDIM + n * NPS + q] * Wc[o * DDIM + n * NPS + q]
               * W_alch[sn * NPS + q];
        sW2[i] = w;
    }
}

__device__ __forceinline__ bool edge_math(
    float vx, float vy, float vz, int pair, const float* sW2,
    float g[3], float t[3])
{
    float d2    = vx * vx + vy * vy + vz * vz + 1e-12f;
    float d     = sqrtf(d2);
    float inv_d = 1.0f / d;

    const float PI = 3.14159265358979323846f;
    const float RCUT = 5.0f, INNER = 4.5f, INVW = 2.0f;
    if (d >= RCUT) return false;
    float taper = 0.5f * (cosf(PI * (d - INNER) * INVW) + 1.0f);
    float fc = (d < INNER) ? 1.0f : taper;

    float theta = (PI / RCUT) * d;
    float s1 = sinf(theta);
    float c1 = cosf(theta);
    float two_c = 2.0f * c1;
    float R[NRAD];
    R[0] = s1 * inv_d;
    float sm2 = 0.0f, sm1 = s1;
    #pragma unroll
    for (int n = 1; n < NRAD; n++) {
        float s = two_c * sm1 - sm2;
        sm2 = sm1; sm1 = s;
        R[n] = s * inv_d;
    }

    #pragma unroll
    for (int o = 0; o < 3; o++) {
        float acc = 0.0f;
        #pragma unroll
        for (int n = 0; n < NRAD; n++)
            acc += R[n] * sW2[(o * NRAD + n) * 16 + pair];
        t[o] = acc;
    }
    g[0] = fc * vy * inv_d;
    g[1] = fc * vz * inv_d;
    g[2] = fc * vx * inv_d;
    return true;
}

__device__ __forceinline__ void atomic_spill(float* out, int c,
                                             int ry, int rz, int rw)
{
    float2 g01 = unpack2((unsigned)ry);
    float2 g2t = unpack2((unsigned)rz);
    float2 t12 = unpack2((unsigned)rw);
    float g[3] = { g01.x, g01.y, g2t.x };
    float t[3] = { g2t.y, t12.x, t12.y };
    float* op = out + (size_t)c * 9;
    #pragma unroll
    for (int m = 0; m < 3; m++)
        #pragma unroll
        for (int o = 0; o < 3; o++)
            atomicAdd(op + m * 3 + o, g[m] * t[o]);
}

// same-key lane mask via bitwise ballots (NB bits); all lanes must be converged
template <int NB>
__device__ __forceinline__ unsigned long long key_mask(int key, bool valid) {
    unsigned long long m = __ballot(valid);
    #pragma unroll
    for (int bit = 0; bit < NB; bit++) {
        unsigned long long b = __ballot((key >> bit) & 1);
        m &= ((key >> bit) & 1) ? b : ~b;
    }
    return m;
}

__global__ __launch_bounds__(PH1_BLK) void vb_phase1(
    const float* __restrict__ vecs,
    const int*   __restrict__ centers,
    const int*   __restrict__ neighbors,
    const int*   __restrict__ species,
    const float* __restrict__ W_alch,
    const float* __restrict__ cemb,
    const float* __restrict__ Wc,
    int*         __restrict__ gcursor,   // (nbin)
    int4*        __restrict__ payload,   // (nbin, cap)
    float*       __restrict__ out,       // spill target (pre-zeroed)
    int E, int cap)
{
    __shared__ float sW2[3 * NRAD * 16];               // 1.5 KB
    __shared__ int4  srec[PH1_REC];                    // 32 KB
    __shared__ int   whist[8][NBIN_MAX];               // 8 KB, per-wave rows
    __shared__ __align__(16) int lcols[NBIN_MAX];      // per-bin totals
    __shared__ int   lexcl[NBIN_MAX];                  // block-excl per bin
    __shared__ int   lbase[NBIN_MAX];                  // global base per bin
    __shared__ int   sTotal;

    int tid  = threadIdx.x;
    int w    = tid >> 6;
    int lane = tid & 63;
    unsigned long long lt = ((unsigned long long)1 << lane) - 1;

    build_w2(sW2, cemb, Wc, W_alch, tid, PH1_BLK);
    for (int i = tid; i < 8 * NBIN_MAX; i += PH1_BLK) ((int*)whist)[i] = 0;
    __syncthreads();

    int4 rec[PH1_U];
    int  keyv[PH1_U], rk[PH1_U];

    #pragma unroll
    for (int u = 0; u < PH1_U; u++) {
        int e = blockIdx.x * PH1_REC + u * PH1_BLK + tid;
        bool valid = false;
        int c = 0;
        if (e < E) {
            float vx = vecs[3 * e + 0];
            float vy = vecs[3 * e + 1];
            float vz = vecs[3 * e + 2];
            c = centers[e];
            int pair = species[c] * 4 + species[neighbors[e]];
            float g[3], t[3];
            if (edge_math(vx, vy, vz, pair, sW2, g, t)) {
                valid = true;
                rec[u].y = (int)pack2(g[0], g[1]);
                rec[u].z = (int)pack2(g[2], t[0]);
                rec[u].w = (int)pack2(t[1], t[2]);
            }
        }
        rec[u].x = valid ? c : -1;
        int key = valid ? (c >> APB_SH) : 0;
        keyv[u] = key;
        unsigned long long m = key_mask<8>(key, valid);
        int rank = (int)__popcll(m & lt);
        int prev = valid ? whist[w][key] : 0;               // wave-lockstep read
        if (valid && rank == 0)
            whist[w][key] = prev + (int)__popcll(m);        // leader plain RMW
        rk[u] = prev + rank;
    }
    __syncthreads();

    // column pass: exclusive over waves; per-bin totals; global reservation
    if (tid < NBIN_MAX) {
        int run = 0;
        #pragma unroll
        for (int w2 = 0; w2 < 8; w2++) {
            int v = whist[w2][tid];
            whist[w2][tid] = run;
            run += v;
        }
        lcols[tid] = run;
        lbase[tid] = run ? atomicAdd(&gcursor[tid], run) : 0;
    }
    __syncthreads();

    // single-wave exclusive scan over 256 bins (4/lane)
    if (tid < 64) {
        int4 v = *(const int4*)&lcols[tid * 4];
        int s0 = v.x, s1 = s0 + v.y, s2 = s1 + v.z, s3 = s2 + v.w;
        int incl = s3;
        #pragma unroll
        for (int off = 1; off < 64; off <<= 1) {
            int t = __shfl_up(incl, off, 64);
            if (tid >= off) incl += t;
        }
        int ex = incl - s3;
        lexcl[tid * 4 + 0] = ex;
        lexcl[tid * 4 + 1] = ex + s0;
        lexcl[tid * 4 + 2] = ex + s1;
        lexcl[tid * 4 + 3] = ex + s2;
        if (tid == 63) sTotal = incl;
    }
    __syncthreads();

    // scatter into LDS sorted by bin (no atomics)
    #pragma unroll
    for (int u = 0; u < PH1_U; u++) {
        if (rec[u].x >= 0) {
            int key = keyv[u];
            int slot = lexcl[key] + whist[w][key] + rk[u];
            srec[slot] = rec[u];
        }
    }
    __syncthreads();

    // coalesced writeout of contiguous per-bin runs
    int total = sTotal;
    for (int i = tid; i < total; i += PH1_BLK) {
        int4 r = srec[i];
        int bin  = r.x >> APB_SH;
        int slot = lbase[bin] + (i - lexcl[bin]);
        if (slot < cap)
            payload[(size_t)bin * cap + slot] = r;
        else
            atomic_spill(out, r.x, r.y, r.z, r.w);
    }
}

__global__ __launch_bounds__(256) void vb_phase2(
    const int*  __restrict__ gcursor,
    const int4* __restrict__ payload,
    float*      __restrict__ partial,    // (nbin*SPLIT, PBSZ)
    int*        __restrict__ done,       // (nbin), pre-zeroed
    float*      __restrict__ out,        // pre-zeroed (+spills)
    int out_elems, int cap)
{
    __shared__ int4 srec2[CAP2];                       // 48 KB
    __shared__ unsigned short sidx[CAP2];              // 6 KB
    __shared__ int whist2[SPLIT][APB];                 // 8 KB, per-wave rows
    __shared__ __align__(16) int acnt[APB];            // 2 KB
    __shared__ int aexcl[APB];                         // 2 KB
    __shared__ int sFlag;

    int b = blockIdx.x / SPLIT;
    int s = blockIdx.x % SPLIT;
    int tid  = threadIdx.x;
    int w    = tid >> 6;
    int lane = tid & 63;
    unsigned long long lt = ((unsigned long long)1 << lane) - 1;

    for (int i = tid; i < SPLIT * APB; i += 256) ((int*)whist2)[i] = 0;
    __syncthreads();

    int count = min(gcursor[b], cap);
    int lo = (int)(((long)count * s) / SPLIT);
    int hi = (int)(((long)count * (s + 1)) / SPLIT);
    int n  = hi - lo;
    int nc = min(n, CAP2);
    const int4* pb = payload + (size_t)b * cap + lo;

    int iters = (nc + 255) >> 8;
    int keyv[IT2_MAX], rk2[IT2_MAX];

    // load + ballot-ranked per-wave histogram (no atomics)
    for (int k = 0; k < iters; k++) {
        int i = k * 256 + tid;
        bool valid = i < nc;
        int key = 0;
        if (valid) {
            int4 r = pb[i];
            srec2[i] = r;
            key = r.x & (APB - 1);
        }
        keyv[k] = key;
        unsigned long long m = key_mask<9>(key, valid);
        int rank = (int)__popcll(m & lt);
        int prev = valid ? whist2[w][key] : 0;
        if (valid && rank == 0)
            whist2[w][key] = prev + (int)__popcll(m);
        rk2[k] = prev + rank;
    }
    __syncthreads();

    // column pass (2 bins/thread): exclusive over waves + per-atom counts
    for (int a = tid; a < APB; a += 256) {
        int run = 0;
        #pragma unroll
        for (int w2 = 0; w2 < SPLIT; w2++) {
            int v = whist2[w2][a];
            whist2[w2][a] = run;
            run += v;
        }
        acnt[a] = run;
    }
    __syncthreads();

    // single-wave exclusive scan over 512 atoms (8/lane)
    if (tid < 64) {
        int base = tid * 8;
        int pre[8];
        int sum = 0;
        #pragma unroll
        for (int j = 0; j < 8; j++) { pre[j] = sum; sum += acnt[base + j]; }
        int incl = sum;
        #pragma unroll
        for (int off = 1; off < 64; off <<= 1) {
            int t = __shfl_up(incl, off, 64);
            if (tid >= off) incl += t;
        }
        int ex = incl - sum;
        #pragma unroll
        for (int j = 0; j < 8; j++) aexcl[base + j] = ex + pre[j];
    }
    __syncthreads();

    // scatter indices sorted by atom (no atomics)
    for (int k = 0; k < iters; k++) {
        int i = k * 256 + tid;
        if (i < nc) {
            int key = keyv[k];
            int slot = aexcl[key] + whist2[w][key] + rk2[k];
            sidx[slot] = (unsigned short)i;
        }
    }
    __syncthreads();

    // per-atom register reduction -> plain stores to this sub-block's partial
    float* pdst = partial + ((size_t)b * SPLIT + s) * PBSZ;
    for (int a = tid; a < APB; a += 256) {
        int st = aexcl[a], en = st + acnt[a];
        float acc[9] = {0,0,0,0,0,0,0,0,0};
        for (int j = st; j < en; j++) {
            int4 r = srec2[sidx[j]];
            float2 g01 = unpack2((unsigned)r.y);
            float2 g2t = unpack2((unsigned)r.z);
            float2 t12 = unpack2((unsigned)r.w);
            float g0 = g01.x, g1 = g01.y, g2 = g2t.x;
            float t0 = g2t.y, t1 = t12.x, t2 = t12.y;
            acc[0] += g0 * t0; acc[1] += g0 * t1; acc[2] += g0 * t2;
            acc[3] += g1 * t0; acc[4] += g1 * t1; acc[5] += g1 * t2;
            acc[6] += g2 * t0; acc[7] += g2 * t1; acc[8] += g2 * t2;
        }
        #pragma unroll
        for (int kk = 0; kk < 9; kk++) pdst[a * 9 + kk] = acc[kk];
    }

    // overflow records (slice > CAP2; statistically never)
    for (int i = CAP2 + tid; i < n; i += 256) {
        int4 r = pb[i];
        atomic_spill(out, r.x, r.y, r.z, r.w);
    }

    // fused reduction: last sub-block of bin b sums the SPLIT partials
    __threadfence();
    __syncthreads();
    if (tid == 0) sFlag = atomicAdd(&done[b], 1);
    __syncthreads();
    if (sFlag == SPLIT - 1) {
        __threadfence();
        size_t ob = ((size_t)b << APB_SH) * 9;
        const float* psrc = partial + (size_t)b * SPLIT * PBSZ;
        for (int i = tid; i < PBSZ; i += 256) {
            size_t gi = ob + i;
            if (gi < (size_t)out_elems) {
                float v = out[gi];   // spill contributions (~always 0)
                #pragma unroll
                for (int s2 = 0; s2 < SPLIT; s2++)
                    v += psrc[(size_t)s2 * PBSZ + i];
                out[gi] = v;
            }
        }
    }
}

// Fallback: direct per-edge global atomics (correct, slow).
__global__ __launch_bounds__(256) void vb_edge_fallback(
    const float* __restrict__ vecs,
    const int*   __restrict__ centers,
    const int*   __restrict__ neighbors,
    const int*   __restrict__ species,
    const float* __restrict__ W_alch,
    const float* __restrict__ cemb,
    const float* __restrict__ Wc,
    float*       __restrict__ out,
    int E)
{
    __shared__ float sW2[3 * NRAD * 16];
    build_w2(sW2, cemb, Wc, W_alch, threadIdx.x, blockDim.x);
    __syncthreads();

    int e = blockIdx.x * blockDim.x + threadIdx.x;
    if (e >= E) return;
    float vx = vecs[3 * e + 0], vy = vecs[3 * e + 1], vz = vecs[3 * e + 2];
    int c = centers[e];
    int pair = species[c] * 4 + species[neighbors[e]];
    float g[3], t[3];
    if (!edge_math(vx, vy, vz, pair, sW2, g, t)) return;
    float* op = out + (size_t)c * 9;
    #pragma unroll
    for (int m = 0; m < 3; m++)
        #pragma unroll
        for (int o = 0; o < 3; o++)
            atomicAdd(op + m * 3 + o, g[m] * t[o]);
}

extern "C" void kernel_launch(void* const* d_in, const int* in_sizes, int n_in,
                              void* d_out, int out_size, void* d_ws, size_t ws_size,
                              hipStream_t stream) {
    const float* vecs      = (const float*)d_in[0];
    const int*   centers   = (const int*)d_in[1];
    const int*   neighbors = (const int*)d_in[2];
    const int*   species   = (const int*)d_in[3];
    const float* W_alch    = (const float*)d_in[6];
    const float* cemb      = (const float*)d_in[7];
    const float* Wc        = (const float*)d_in[8];
    float*       out       = (float*)d_out;

    int E = in_sizes[1];
    int A = in_sizes[3];
    int nbin = (A + APB - 1) >> APB_SH;

    // ws: [gcursor nbin | done nbin @2048 | 4KB][payload nbin*cap*16B]
    //     [partial nbin*SPLIT*PBSZ*4B]
    size_t part_bytes = (size_t)nbin * SPLIT * PBSZ * sizeof(float);
    long cap = 0;
    long fixed = 4096 + (long)part_bytes;
    if ((long)ws_size > fixed) {
        cap = ((long)ws_size - fixed) / 16 / nbin;
        cap &= ~7L;
        if (cap > 16384) cap = 16384;
    }
    long mean = (long)E / nbin + 1;

    hipMemsetAsync(d_out, 0, (size_t)out_size * sizeof(float), stream);

    if (nbin <= NBIN_MAX && cap >= mean + mean / 16) {
        int*   gcursor = (int*)d_ws;
        int*   done    = (int*)((char*)d_ws + 2048);
        int4*  payload = (int4*)((char*)d_ws + 4096);
        float* partial = (float*)((char*)d_ws + 4096 + (size_t)nbin * cap * 16);
        hipMemsetAsync(d_ws, 0, 4096, stream);

        int g1 = (E + PH1_REC - 1) / PH1_REC;
        vb_phase1<<<g1, PH1_BLK, 0, stream>>>(vecs, centers, neighbors, species,
                                              W_alch, cemb, Wc,
                                              gcursor, payload, out, E, (int)cap);
        vb_phase2<<<nbin * SPLIT, 256, 0, stream>>>(gcursor, payload, partial,
                                                    done, out, out_size, (int)cap);
    } else {
        int grid = (E + 255) / 256;
        vb_edge_fallback<<<grid, 256, 0, stream>>>(vecs, centers, neighbors, species,
                                                   W_alch, cemb, Wc, out, E);
    }
}

// Round 7
// 156.259 us; speedup vs baseline: 2.0035x; 2.0035x over previous
//
#include <hip/hip_runtime.h>
#include <hip/hip_fp16.h>

// VectorBasis R7. R5 structure (proven 146us) with ONE change: phase2's two
// per-record LDS atomics (histogram + scatter cursor) replaced by ballot
// clustering with per-wave histogram rows. R6 proved this logic correct but
// carried per-record key/rank in runtime-indexed local arrays -> scratch
// spill (205us latency-bound). R7 recomputes key+rank in each pass
// (stateless loops, nothing spillable). Phase1/reduce are R5 verbatim.

constexpr int NSP  = 4;
constexpr int NRAD = 8;
constexpr int NPS  = 4;
constexpr int DDIM = NRAD * NPS;       // 32

constexpr int APB      = 512;          // atoms per bin
constexpr int APB_SH   = 9;
constexpr int NBIN_MAX = 256;
constexpr int SPLIT    = 4;            // phase2 sub-blocks per bin
constexpr int NW2      = 4;            // waves per phase2 block (256 thr)
constexpr int PH1_BLK  = 512;
constexpr int PH1_U    = 4;
constexpr int PH1_REC  = PH1_BLK * PH1_U;  // 2048 records per phase1 block
constexpr int CAP2     = 3072;         // phase2 per-sub-block record capacity

__device__ __forceinline__ unsigned pack2(float a, float b) {
    union { __half2 h; unsigned u; } cv;
    cv.h = __floats2half2_rn(a, b);
    return cv.u;
}
__device__ __forceinline__ float2 unpack2(unsigned u) {
    union { unsigned u; __half2 h; } cv;
    cv.u = u;
    return __half22float2(cv.h);
}

// W2[(o*8+n)*16 + (sc*4+sn)] = sum_q cemb[sc][n*4+q]*Wc[o][n*4+q]*alch[sn][q]
__device__ __forceinline__ void build_w2(
    float* sW2, const float* cemb, const float* Wc, const float* W_alch,
    int tid, int nthreads)
{
    for (int i = tid; i < 3 * NRAD * 16; i += nthreads) {
        int p  = i & 15;
        int n  = (i >> 4) & 7;
        int o  = i >> 7;
        int sc = p >> 2, sn = p & 3;
        float w = 0.0f;
        #pragma unroll
        for (int q = 0; q < NPS; q++)
            w += cemb[sc * DDIM + n * NPS + q] * Wc[o * DDIM + n * NPS + q]
               * W_alch[sn * NPS + q];
        sW2[i] = w;
    }
}

__device__ __forceinline__ bool edge_math(
    float vx, float vy, float vz, int pair, const float* sW2,
    float g[3], float t[3])
{
    float d2    = vx * vx + vy * vy + vz * vz + 1e-12f;
    float d     = sqrtf(d2);
    float inv_d = 1.0f / d;

    const float PI = 3.14159265358979323846f;
    const float RCUT = 5.0f, INNER = 4.5f, INVW = 2.0f;
    if (d >= RCUT) return false;
    float taper = 0.5f * (cosf(PI * (d - INNER) * INVW) + 1.0f);
    float fc = (d < INNER) ? 1.0f : taper;

    float theta = (PI / RCUT) * d;
    float s1 = sinf(theta);
    float c1 = cosf(theta);
    float two_c = 2.0f * c1;
    float R[NRAD];
    R[0] = s1 * inv_d;
    float sm2 = 0.0f, sm1 = s1;
    #pragma unroll
    for (int n = 1; n < NRAD; n++) {
        float s = two_c * sm1 - sm2;
        sm2 = sm1; sm1 = s;
        R[n] = s * inv_d;
    }

    #pragma unroll
    for (int o = 0; o < 3; o++) {
        float acc = 0.0f;
        #pragma unroll
        for (int n = 0; n < NRAD; n++)
            acc += R[n] * sW2[(o * NRAD + n) * 16 + pair];
        t[o] = acc;
    }
    g[0] = fc * vy * inv_d;
    g[1] = fc * vz * inv_d;
    g[2] = fc * vx * inv_d;
    return true;
}

__device__ __forceinline__ void atomic_spill(float* out, int c,
                                             int ry, int rz, int rw)
{
    float2 g01 = unpack2((unsigned)ry);
    float2 g2t = unpack2((unsigned)rz);
    float2 t12 = unpack2((unsigned)rw);
    float g[3] = { g01.x, g01.y, g2t.x };
    float t[3] = { g2t.y, t12.x, t12.y };
    float* op = out + (size_t)c * 9;
    #pragma unroll
    for (int m = 0; m < 3; m++)
        #pragma unroll
        for (int o = 0; o < 3; o++)
            atomicAdd(op + m * 3 + o, g[m] * t[o]);
}

// same-key lane mask via bitwise ballots; all lanes must be converged
template <int NB>
__device__ __forceinline__ unsigned long long key_mask(int key, bool valid) {
    unsigned long long m = __ballot(valid);
    #pragma unroll
    for (int bit = 0; bit < NB; bit++) {
        unsigned long long b = __ballot((key >> bit) & 1);
        m &= ((key >> bit) & 1) ? b : ~b;
    }
    return m;
}

// ===================== phase1: R5 verbatim (proven 45us) =====================
__global__ __launch_bounds__(PH1_BLK) void vb_phase1(
    const float* __restrict__ vecs,
    const int*   __restrict__ centers,
    const int*   __restrict__ neighbors,
    const int*   __restrict__ species,
    const float* __restrict__ W_alch,
    const float* __restrict__ cemb,
    const float* __restrict__ Wc,
    int*         __restrict__ gcursor,   // (nbin)
    int4*        __restrict__ payload,   // (nbin, cap) 16B records
    float*       __restrict__ out,       // overflow target (pre-zeroed)
    int E, int cap)
{
    __shared__ float sW2[3 * NRAD * 16];            // 1.5 KB
    __shared__ int4  srec[PH1_REC];                 // 32 KB
    __shared__ int lcount[NBIN_MAX], lscan[NBIN_MAX], lexcl[NBIN_MAX],
                   lbase[NBIN_MAX], lcur[NBIN_MAX]; // 5 KB

    int tid = threadIdx.x;
    build_w2(sW2, cemb, Wc, W_alch, tid, PH1_BLK);
    for (int i = tid; i < NBIN_MAX; i += PH1_BLK) lcount[i] = 0;
    __syncthreads();

    int4 rec[PH1_U];
    #pragma unroll
    for (int u = 0; u < PH1_U; u++) {
        int e = blockIdx.x * PH1_REC + u * PH1_BLK + tid;
        rec[u].x = -1;
        if (e < E) {
            float vx = vecs[3 * e + 0];
            float vy = vecs[3 * e + 1];
            float vz = vecs[3 * e + 2];
            int c  = centers[e];
            int pair = species[c] * 4 + species[neighbors[e]];
            float g[3], t[3];
            if (edge_math(vx, vy, vz, pair, sW2, g, t)) {
                rec[u].x = c;
                rec[u].y = (int)pack2(g[0], g[1]);
                rec[u].z = (int)pack2(g[2], t[0]);
                rec[u].w = (int)pack2(t[1], t[2]);
                atomicAdd(&lcount[c >> APB_SH], 1);
            }
        }
    }
    __syncthreads();

    if (tid < NBIN_MAX) lscan[tid] = lcount[tid];
    __syncthreads();
    for (int off = 1; off < NBIN_MAX; off <<= 1) {
        int v = 0;
        if (tid < NBIN_MAX) {
            v = lscan[tid];
            if (tid >= off) v += lscan[tid - off];
        }
        __syncthreads();
        if (tid < NBIN_MAX) lscan[tid] = v;
        __syncthreads();
    }
    if (tid < NBIN_MAX) {
        int ex = lscan[tid] - lcount[tid];
        lexcl[tid] = ex;
        lcur[tid]  = ex;
        int n = lcount[tid];
        lbase[tid] = n ? atomicAdd(&gcursor[tid], n) : 0;
    }
    __syncthreads();

    #pragma unroll
    for (int u = 0; u < PH1_U; u++) {
        if (rec[u].x >= 0) {
            int bin = rec[u].x >> APB_SH;
            int p = atomicAdd(&lcur[bin], 1);
            srec[p] = rec[u];
        }
    }
    __syncthreads();

    int total = lscan[NBIN_MAX - 1];
    for (int i = tid; i < total; i += PH1_BLK) {
        int4 r = srec[i];
        int bin  = r.x >> APB_SH;
        int slot = lbase[bin] + (i - lexcl[bin]);
        if (slot < cap)
            payload[(size_t)bin * cap + slot] = r;
        else
            atomic_spill(out, r.x, r.y, r.z, r.w);
    }
}

// ============ phase2: ballot-ranked counting sort, zero atomics ============
__global__ __launch_bounds__(256) void vb_phase2(
    const int*  __restrict__ gcursor,
    const int4* __restrict__ payload,
    float*      __restrict__ partial,   // (SPLIT, out_elems), fully overwritten
    float*      __restrict__ out,       // overflow target (pre-zeroed)
    int out_elems, int cap)
{
    __shared__ int4 srec2[CAP2];                    // 48 KB
    __shared__ unsigned short sidx[CAP2];           // 6 KB
    __shared__ int whist2[NW2][APB];                // 8 KB, per-wave rows
    __shared__ __align__(16) int acnt[APB];         // 2 KB
    __shared__ int aexcl[APB];                      // 2 KB

    int b = blockIdx.x / SPLIT;
    int s = blockIdx.x % SPLIT;
    int tid  = threadIdx.x;
    int w    = tid >> 6;
    int lane = tid & 63;
    unsigned long long lt = ((unsigned long long)1 << lane) - 1;

    for (int i = tid; i < NW2 * APB; i += 256) ((int*)whist2)[i] = 0;
    __syncthreads();

    int count = min(gcursor[b], cap);
    int lo = (int)(((long)count * s) / SPLIT);
    int hi = (int)(((long)count * (s + 1)) / SPLIT);
    int n  = hi - lo;
    int nc = min(n, CAP2);
    const int4* pb = payload + (size_t)b * cap + lo;

    // pass A: load + per-wave histogram via ballot (leader plain RMW; no
    // per-record state carried -> nothing can spill to scratch)
    for (int i0 = 0; i0 < nc; i0 += 256) {
        int i = i0 + tid;
        bool valid = i < nc;
        int key = 0;
        if (valid) {
            int4 r = pb[i];
            srec2[i] = r;
            key = r.x & (APB - 1);
        }
        unsigned long long m = key_mask<9>(key, valid);
        int rank = (int)__popcll(m & lt);
        int prev = valid ? whist2[w][key] : 0;      // wave-lockstep read
        if (valid && rank == 0)
            whist2[w][key] = prev + (int)__popcll(m);
    }
    __syncthreads();

    // column pass: exclusive over waves; per-atom counts
    for (int a = tid; a < APB; a += 256) {
        int run = 0;
        #pragma unroll
        for (int w2 = 0; w2 < NW2; w2++) {
            int v = whist2[w2][a];
            whist2[w2][a] = run;
            run += v;
        }
        acnt[a] = run;
    }
    __syncthreads();

    // single-wave exclusive scan over 512 atoms (8/lane)
    if (tid < 64) {
        int base = tid * 8;
        int pre[8];
        int sum = 0;
        #pragma unroll
        for (int j = 0; j < 8; j++) { pre[j] = sum; sum += acnt[base + j]; }
        int incl = sum;
        #pragma unroll
        for (int off = 1; off < 64; off <<= 1) {
            int t = __shfl_up(incl, off, 64);
            if (tid >= off) incl += t;
        }
        int ex = incl - sum;
        #pragma unroll
        for (int j = 0; j < 8; j++) aexcl[base + j] = ex + pre[j];
    }
    __syncthreads();

    // pass B: scatter indices sorted by atom; key+rank recomputed (stateless)
    for (int i0 = 0; i0 < nc; i0 += 256) {
        int i = i0 + tid;
        bool valid = i < nc;
        int key = valid ? (srec2[i].x & (APB - 1)) : 0;
        unsigned long long m = key_mask<9>(key, valid);
        int rank = (int)__popcll(m & lt);
        int prev = valid ? whist2[w][key] : 0;
        if (valid && rank == 0)
            whist2[w][key] = prev + (int)__popcll(m);
        if (valid)
            sidx[aexcl[key] + prev + rank] = (unsigned short)i;
    }
    __syncthreads();

    // per-atom register reduction -> plain stores to this sub-block's partial
    for (int a = tid; a < APB; a += 256) {
        int st = aexcl[a], en = st + acnt[a];
        float acc[9] = {0,0,0,0,0,0,0,0,0};
        for (int j = st; j < en; j++) {
            int4 r = srec2[sidx[j]];
            float2 g01 = unpack2((unsigned)r.y);
            float2 g2t = unpack2((unsigned)r.z);
            float2 t12 = unpack2((unsigned)r.w);
            float g0 = g01.x, g1 = g01.y, g2 = g2t.x;
            float t0 = g2t.y, t1 = t12.x, t2 = t12.y;
            acc[0] += g0 * t0; acc[1] += g0 * t1; acc[2] += g0 * t2;
            acc[3] += g1 * t0; acc[4] += g1 * t1; acc[5] += g1 * t2;
            acc[6] += g2 * t0; acc[7] += g2 * t1; acc[8] += g2 * t2;
        }
        size_t gi = ((size_t)(b << APB_SH) + a) * 9;
        if (gi < (size_t)out_elems) {
            float* pd = partial + (size_t)s * out_elems + gi;
            #pragma unroll
            for (int k = 0; k < 9; k++) pd[k] = acc[k];
        }
    }

    // overflow records (slice > CAP2; statistically never)
    for (int i = CAP2 + tid; i < n; i += 256) {
        int4 r = pb[i];
        atomic_spill(out, r.x, r.y, r.z, r.w);
    }
}

__global__ __launch_bounds__(256) void vb_reduce(
    const float* __restrict__ partial, float* __restrict__ out, int n)
{
    int i = blockIdx.x * blockDim.x + threadIdx.x;
    if (i >= n) return;
    out[i] += partial[i] + partial[(size_t)n + i]
            + partial[2 * (size_t)n + i] + partial[3 * (size_t)n + i];
}

// Fallback: direct per-edge global atomics (correct, slow).
__global__ __launch_bounds__(256) void vb_edge_fallback(
    const float* __restrict__ vecs,
    const int*   __restrict__ centers,
    const int*   __restrict__ neighbors,
    const int*   __restrict__ species,
    const float* __restrict__ W_alch,
    const float* __restrict__ cemb,
    const float* __restrict__ Wc,
    float*       __restrict__ out,
    int E)
{
    __shared__ float sW2[3 * NRAD * 16];
    build_w2(sW2, cemb, Wc, W_alch, threadIdx.x, blockDim.x);
    __syncthreads();

    int e = blockIdx.x * blockDim.x + threadIdx.x;
    if (e >= E) return;
    float vx = vecs[3 * e + 0], vy = vecs[3 * e + 1], vz = vecs[3 * e + 2];
    int c = centers[e];
    int pair = species[c] * 4 + species[neighbors[e]];
    float g[3], t[3];
    if (!edge_math(vx, vy, vz, pair, sW2, g, t)) return;
    float* op = out + (size_t)c * 9;
    #pragma unroll
    for (int m = 0; m < 3; m++)
        #pragma unroll
        for (int o = 0; o < 3; o++)
            atomicAdd(op + m * 3 + o, g[m] * t[o]);
}

extern "C" void kernel_launch(void* const* d_in, const int* in_sizes, int n_in,
                              void* d_out, int out_size, void* d_ws, size_t ws_size,
                              hipStream_t stream) {
    const float* vecs      = (const float*)d_in[0];
    const int*   centers   = (const int*)d_in[1];
    const int*   neighbors = (const int*)d_in[2];
    const int*   species   = (const int*)d_in[3];
    const float* W_alch    = (const float*)d_in[6];
    const float* cemb      = (const float*)d_in[7];
    const float* Wc        = (const float*)d_in[8];
    float*       out       = (float*)d_out;

    int E = in_sizes[1];
    int A = in_sizes[3];
    int nbin = (A + APB - 1) >> APB_SH;

    // ws layout: [gcursor 4KB][payload nbin*cap*16B][partial SPLIT*out*4B]
    size_t out_bytes = (size_t)out_size * sizeof(float);
    long cap = 0;
    long fixed = 4096 + (long)SPLIT * out_bytes;
    if ((long)ws_size > fixed) {
        cap = ((long)ws_size - fixed) / 16 / nbin;
        cap &= ~7L;
        if (cap > 16384) cap = 16384;
    }
    long mean = (long)E / nbin + 1;

    hipMemsetAsync(d_out, 0, out_bytes, stream);

    if (nbin <= NBIN_MAX && cap >= mean + mean / 16) {
        int*   gcursor = (int*)d_ws;
        int4*  payload = (int4*)((char*)d_ws + 4096);
        float* partial = (float*)((char*)d_ws + 4096 + (size_t)nbin * cap * 16);
        hipMemsetAsync(d_ws, 0, 4096, stream);

        int g1 = (E + PH1_REC - 1) / PH1_REC;
        vb_phase1<<<g1, PH1_BLK, 0, stream>>>(vecs, centers, neighbors, species,
                                              W_alch, cemb, Wc,
                                              gcursor, payload, out, E, (int)cap);
        vb_phase2<<<nbin * SPLIT, 256, 0, stream>>>(gcursor, payload, partial,
                                                    out, out_size, (int)cap);
        int rg = (out_size + 255) / 256;
        vb_reduce<<<rg, 256, 0, stream>>>(partial, out, out_size);
    } else {
        int grid = (E + 255) / 256;
        vb_edge_fallback<<<grid, 256, 0, stream>>>(vecs, centers, neighbors, species,
                                                   W_alch, cemb, Wc, out, E);
    }
}

// Round 8
// 144.163 us; speedup vs baseline: 2.1716x; 1.0839x over previous
//
#include <hip/hip_runtime.h>
#include <hip/hip_fp16.h>

// VectorBasis R8. Structure: 2 kernels + 1 tiny memset (was 5 nodes).
// Bins are 128 atoms (nbin=782). Phase1 (R5-proven shape): per-block counting
// sort of 2048 edge records by bin -> coalesced payload append (1 global
// atomic per block-bin). Phase2: one block per bin OWNS its 128 atoms:
// counting sort by atom (2 int LDS atomics/record — R7 A/B showed this beats
// ballot ranking), register accumulation, direct full overwrite of out
// (no partial buffer / reduce kernel / d_out memset). Spills (statistically
// never) go to a global overflow list each phase2 block checks (1 load).

constexpr int NSP  = 4;
constexpr int NRAD = 8;
constexpr int NPS  = 4;
constexpr int DDIM = NRAD * NPS;       // 32

constexpr int APB      = 128;          // atoms per bin
constexpr int APB_SH   = 7;
constexpr int NBIN_PAD = 832;          // 64*13 >= 782
constexpr int PH1_BLK  = 512;
constexpr int PH1_U    = 4;
constexpr int PH1_REC  = PH1_BLK * PH1_U;  // 2048
constexpr int CAP2     = 2560;         // phase2 LDS chunk (records)
constexpr int OVF_CAP  = 65536;        // global overflow list capacity

__device__ __forceinline__ unsigned pack2(float a, float b) {
    union { __half2 h; unsigned u; } cv;
    cv.h = __floats2half2_rn(a, b);
    return cv.u;
}
__device__ __forceinline__ float2 unpack2(unsigned u) {
    union { unsigned u; __half2 h; } cv;
    cv.u = u;
    return __half22float2(cv.h);
}

__device__ __forceinline__ void build_w2(
    float* sW2, const float* cemb, const float* Wc, const float* W_alch,
    int tid, int nthreads)
{
    for (int i = tid; i < 3 * NRAD * 16; i += nthreads) {
        int p  = i & 15;
        int n  = (i >> 4) & 7;
        int o  = i >> 7;
        int sc = p >> 2, sn = p & 3;
        float w = 0.0f;
        #pragma unroll
        for (int q = 0; q < NPS; q++)
            w += cemb[sc * DDIM + n * NPS + q] * Wc[o * DDIM + n * NPS + q]
               * W_alch[sn * NPS + q];
        sW2[i] = w;
    }
}

__device__ __forceinline__ bool edge_math(
    float vx, float vy, float vz, int pair, const float* sW2,
    float g[3], float t[3])
{
    float d2    = vx * vx + vy * vy + vz * vz + 1e-12f;
    float d     = sqrtf(d2);
    float inv_d = 1.0f / d;

    const float PI = 3.14159265358979323846f;
    const float RCUT = 5.0f, INNER = 4.5f, INVW = 2.0f;
    if (d >= RCUT) return false;
    float taper = 0.5f * (cosf(PI * (d - INNER) * INVW) + 1.0f);
    float fc = (d < INNER) ? 1.0f : taper;

    float theta = (PI / RCUT) * d;
    float s1 = sinf(theta);
    float c1 = cosf(theta);
    float two_c = 2.0f * c1;
    float R[NRAD];
    R[0] = s1 * inv_d;
    float sm2 = 0.0f, sm1 = s1;
    #pragma unroll
    for (int n = 1; n < NRAD; n++) {
        float s = two_c * sm1 - sm2;
        sm2 = sm1; sm1 = s;
        R[n] = s * inv_d;
    }

    #pragma unroll
    for (int o = 0; o < 3; o++) {
        float acc = 0.0f;
        #pragma unroll
        for (int n = 0; n < NRAD; n++)
            acc += R[n] * sW2[(o * NRAD + n) * 16 + pair];
        t[o] = acc;
    }
    g[0] = fc * vy * inv_d;
    g[1] = fc * vz * inv_d;
    g[2] = fc * vx * inv_d;
    return true;
}

// ===================== phase1: counting sort by 128-atom bin ================
__global__ __launch_bounds__(PH1_BLK) void vb_phase1(
    const float* __restrict__ vecs,
    const int*   __restrict__ centers,
    const int*   __restrict__ neighbors,
    const int*   __restrict__ species,
    const float* __restrict__ W_alch,
    const float* __restrict__ cemb,
    const float* __restrict__ Wc,
    int*         __restrict__ gcursor,   // (nbin)
    int*         __restrict__ ovfcnt,    // 1 int
    int4*        __restrict__ ovf,       // (OVF_CAP)
    int4*        __restrict__ payload,   // (nbin, cap)
    int E, int nbin, int cap)
{
    __shared__ float sW2[3 * NRAD * 16];                // 1.5 KB
    __shared__ int4  srec[PH1_REC];                     // 32 KB
    __shared__ int lcount[NBIN_PAD], lexcl[NBIN_PAD],
                   lbase[NBIN_PAD], lcur[NBIN_PAD];     // 13.3 KB
    __shared__ int sTotal;

    int tid = threadIdx.x;
    build_w2(sW2, cemb, Wc, W_alch, tid, PH1_BLK);
    for (int i = tid; i < NBIN_PAD; i += PH1_BLK) lcount[i] = 0;
    __syncthreads();

    int4 rec[PH1_U];
    #pragma unroll
    for (int u = 0; u < PH1_U; u++) {
        int e = blockIdx.x * PH1_REC + u * PH1_BLK + tid;
        rec[u].x = -1;
        if (e < E) {
            float vx = vecs[3 * e + 0];
            float vy = vecs[3 * e + 1];
            float vz = vecs[3 * e + 2];
            int c  = centers[e];
            int pair = species[c] * 4 + species[neighbors[e]];
            float g[3], t[3];
            if (edge_math(vx, vy, vz, pair, sW2, g, t)) {
                rec[u].x = c;
                rec[u].y = (int)pack2(g[0], g[1]);
                rec[u].z = (int)pack2(g[2], t[0]);
                rec[u].w = (int)pack2(t[1], t[2]);
                atomicAdd(&lcount[c >> APB_SH], 1);
            }
        }
    }
    __syncthreads();

    // single-wave exclusive scan over NBIN_PAD bins (13/lane)
    if (tid < 64) {
        int base = tid * 13;
        int pre[13];
        int sum = 0;
        #pragma unroll
        for (int j = 0; j < 13; j++) { pre[j] = sum; sum += lcount[base + j]; }
        int incl = sum;
        #pragma unroll
        for (int off = 1; off < 64; off <<= 1) {
            int t = __shfl_up(incl, off, 64);
            if (tid >= off) incl += t;
        }
        int ex = incl - sum;
        #pragma unroll
        for (int j = 0; j < 13; j++) lexcl[base + j] = ex + pre[j];
        if (tid == 63) sTotal = incl;
    }
    __syncthreads();

    // global slot reservation (1 atomic per non-empty bin) + cursor init
    for (int i = tid; i < nbin; i += PH1_BLK) {
        lcur[i] = lexcl[i];
        int n = lcount[i];
        lbase[i] = n ? atomicAdd(&gcursor[i], n) : 0;
    }
    __syncthreads();

    // scatter records into LDS sorted by bin
    #pragma unroll
    for (int u = 0; u < PH1_U; u++) {
        if (rec[u].x >= 0) {
            int bin = rec[u].x >> APB_SH;
            int p = atomicAdd(&lcur[bin], 1);
            srec[p] = rec[u];
        }
    }
    __syncthreads();

    // coalesced writeout of contiguous per-bin runs
    int total = sTotal;
    for (int i = tid; i < total; i += PH1_BLK) {
        int4 r = srec[i];
        int bin  = r.x >> APB_SH;
        int slot = lbase[bin] + (i - lexcl[bin]);
        if (slot < cap) {
            payload[(size_t)bin * cap + slot] = r;
        } else {
            int p = atomicAdd(ovfcnt, 1);
            if (p < OVF_CAP) ovf[p] = r;   // capacity 65536: never exceeded
        }
    }
}

// ============ phase2: per-bin counting sort + direct out overwrite ==========
__global__ __launch_bounds__(256) void vb_phase2(
    const int*  __restrict__ gcursor,
    const int*  __restrict__ ovfcnt,
    const int4* __restrict__ ovf,
    const int4* __restrict__ payload,
    float*      __restrict__ out,        // (A,9), fully overwritten
    int A, int cap)
{
    __shared__ int4 srec2[CAP2];                    // 40 KB
    __shared__ unsigned short sidx[CAP2];           // 5 KB
    __shared__ int cnt[APB], aexcl[APB], ccur[APB]; // 1.5 KB
    __shared__ float sout[APB * 9];                 // 4.5 KB

    int b   = blockIdx.x;
    int tid = threadIdx.x;
    int count = min(gcursor[b], cap);
    const int4* pb = payload + (size_t)b * cap;

    float acc[9] = {0,0,0,0,0,0,0,0,0};
    int myatom = (b << APB_SH) + tid;   // meaningful for tid < APB

    for (int base = 0; base < count; base += CAP2) {
        int nc = min(count - base, CAP2);
        if (tid < APB) cnt[tid] = 0;
        __syncthreads();

        // load + histogram (1 int LDS atomic / record)
        for (int i = tid; i < nc; i += 256) {
            int4 r = pb[base + i];
            srec2[i] = r;
            atomicAdd(&cnt[r.x & (APB - 1)], 1);
        }
        __syncthreads();

        // single-wave exclusive scan over 128 keys (2/lane)
        if (tid < 64) {
            int c0 = cnt[2 * tid], c1 = cnt[2 * tid + 1];
            int s1 = c0 + c1;
            int incl = s1;
            #pragma unroll
            for (int off = 1; off < 64; off <<= 1) {
                int t = __shfl_up(incl, off, 64);
                if (tid >= off) incl += t;
            }
            int ex = incl - s1;
            aexcl[2 * tid]     = ex;
            aexcl[2 * tid + 1] = ex + c0;
        }
        __syncthreads();
        if (tid < APB) ccur[tid] = aexcl[tid];
        __syncthreads();

        // scatter indices sorted by atom (1 int LDS atomic / record)
        for (int i = tid; i < nc; i += 256) {
            int k = srec2[i].x & (APB - 1);
            sidx[atomicAdd(&ccur[k], 1)] = (unsigned short)i;
        }
        __syncthreads();

        // per-atom register accumulation (threads 0..127 own one atom each)
        if (tid < APB) {
            int st = aexcl[tid], en = st + cnt[tid];
            for (int j = st; j < en; j++) {
                int4 r = srec2[sidx[j]];
                float2 g01 = unpack2((unsigned)r.y);
                float2 g2t = unpack2((unsigned)r.z);
                float2 t12 = unpack2((unsigned)r.w);
                float g0 = g01.x, g1 = g01.y, g2 = g2t.x;
                float t0 = g2t.y, t1 = t12.x, t2 = t12.y;
                acc[0] += g0 * t0; acc[1] += g0 * t1; acc[2] += g0 * t2;
                acc[3] += g1 * t0; acc[4] += g1 * t1; acc[5] += g1 * t2;
                acc[6] += g2 * t0; acc[7] += g2 * t1; acc[8] += g2 * t2;
            }
        }
        __syncthreads();   // srec2/sidx reused next chunk
    }

    // overflow list (statistically empty): broadcast scan
    int novf = min(*ovfcnt, OVF_CAP);
    for (int i = 0; i < novf; i++) {
        int4 r = ovf[i];
        if (tid < APB && r.x == myatom) {
            float2 g01 = unpack2((unsigned)r.y);
            float2 g2t = unpack2((unsigned)r.z);
            float2 t12 = unpack2((unsigned)r.w);
            float g0 = g01.x, g1 = g01.y, g2 = g2t.x;
            float t0 = g2t.y, t1 = t12.x, t2 = t12.y;
            acc[0] += g0 * t0; acc[1] += g0 * t1; acc[2] += g0 * t2;
            acc[3] += g1 * t0; acc[4] += g1 * t1; acc[5] += g1 * t2;
            acc[6] += g2 * t0; acc[7] += g2 * t1; acc[8] += g2 * t2;
        }
    }

    // direct coalesced overwrite of out
    if (tid < APB) {
        #pragma unroll
        for (int k = 0; k < 9; k++) sout[tid * 9 + k] = acc[k];
    }
    __syncthreads();
    size_t gbase = (size_t)b * APB * 9;
    size_t lim = (size_t)A * 9;
    for (int i = tid; i < APB * 9; i += 256) {
        size_t gi = gbase + i;
        if (gi < lim) out[gi] = sout[i];
    }
}

// Fallback: direct per-edge global atomics (correct, slow).
__global__ __launch_bounds__(256) void vb_edge_fallback(
    const float* __restrict__ vecs,
    const int*   __restrict__ centers,
    const int*   __restrict__ neighbors,
    const int*   __restrict__ species,
    const float* __restrict__ W_alch,
    const float* __restrict__ cemb,
    const float* __restrict__ Wc,
    float*       __restrict__ out,
    int E)
{
    __shared__ float sW2[3 * NRAD * 16];
    build_w2(sW2, cemb, Wc, W_alch, threadIdx.x, blockDim.x);
    __syncthreads();

    int e = blockIdx.x * blockDim.x + threadIdx.x;
    if (e >= E) return;
    float vx = vecs[3 * e + 0], vy = vecs[3 * e + 1], vz = vecs[3 * e + 2];
    int c = centers[e];
    int pair = species[c] * 4 + species[neighbors[e]];
    float g[3], t[3];
    if (!edge_math(vx, vy, vz, pair, sW2, g, t)) return;
    float* op = out + (size_t)c * 9;
    #pragma unroll
    for (int m = 0; m < 3; m++)
        #pragma unroll
        for (int o = 0; o < 3; o++)
            atomicAdd(op + m * 3 + o, g[m] * t[o]);
}

extern "C" void kernel_launch(void* const* d_in, const int* in_sizes, int n_in,
                              void* d_out, int out_size, void* d_ws, size_t ws_size,
                              hipStream_t stream) {
    const float* vecs      = (const float*)d_in[0];
    const int*   centers   = (const int*)d_in[1];
    const int*   neighbors = (const int*)d_in[2];
    const int*   species   = (const int*)d_in[3];
    const float* W_alch    = (const float*)d_in[6];
    const float* cemb      = (const float*)d_in[7];
    const float* Wc        = (const float*)d_in[8];
    float*       out       = (float*)d_out;

    int E = in_sizes[1];
    int A = in_sizes[3];
    int nbin = (A + APB - 1) >> APB_SH;

    // ws: [gcursor nbin ints | ovfcnt @3840 | pad to 4KB][ovf 1MB][payload]
    size_t ovf_off = 4096;
    size_t pay_off = ovf_off + (size_t)OVF_CAP * 16;
    long cap = 0;
    if (ws_size > pay_off) {
        cap = (long)((ws_size - pay_off) / 16) / nbin;
        cap &= ~7L;
        if (cap > 4096) cap = 4096;
    }
    long mean = (long)E / nbin + 1;

    if (nbin <= NBIN_PAD && nbin <= 3840 / 4 && cap >= mean + mean / 8) {
        int*  gcursor = (int*)d_ws;
        int*  ovfcnt  = (int*)((char*)d_ws + 3840);
        int4* ovf     = (int4*)((char*)d_ws + ovf_off);
        int4* payload = (int4*)((char*)d_ws + pay_off);
        hipMemsetAsync(d_ws, 0, 4096, stream);

        int g1 = (E + PH1_REC - 1) / PH1_REC;
        vb_phase1<<<g1, PH1_BLK, 0, stream>>>(vecs, centers, neighbors, species,
                                              W_alch, cemb, Wc,
                                              gcursor, ovfcnt, ovf, payload,
                                              E, nbin, (int)cap);
        vb_phase2<<<nbin, 256, 0, stream>>>(gcursor, ovfcnt, ovf, payload,
                                            out, A, (int)cap);
    } else {
        hipMemsetAsync(d_out, 0, (size_t)out_size * sizeof(float), stream);
        int grid = (E + 255) / 256;
        vb_edge_fallback<<<grid, 256, 0, stream>>>(vecs, centers, neighbors, species,
                                                   W_alch, cemb, Wc, out, E);
    }
}